// Round 1
// baseline (78.465 us; speedup 1.0000x reference)
//
#include <hip/hip_runtime.h>
#include <hip/hip_bf16.h>

#define COEFF 1.0f
#define MAX_COLORS 64

__global__ __launch_bounds__(256) void nps_partial_kernel(
    const float* __restrict__ adv,
    const float* __restrict__ colors,
    float* __restrict__ partials,
    int nquads, int npix, int M)
{
    __shared__ float4 col[MAX_COLORS];
    if ((int)threadIdx.x < M) {
        float cx = colors[3 * threadIdx.x + 0];
        float cy = colors[3 * threadIdx.x + 1];
        float cz = colors[3 * threadIdx.x + 2];
        col[threadIdx.x] = make_float4(cx, cy, cz, 0.f);
    }
    __syncthreads();

    const float4* __restrict__ in4 = (const float4*)adv;
    float lsum = 0.f;
    int tid = blockIdx.x * blockDim.x + threadIdx.x;
    int stride = gridDim.x * blockDim.x;

    for (int q = tid; q < nquads; q += stride) {
        float4 a = in4[3 * q + 0];
        float4 b = in4[3 * q + 1];
        float4 c = in4[3 * q + 2];
        // 12 floats = 4 pixel triples (memory-order, matches reshape(-1,3))
        float px0 = a.x, py0 = a.y, pz0 = a.z;
        float px1 = a.w, py1 = b.x, pz1 = b.y;
        float px2 = b.z, py2 = b.w, pz2 = c.x;
        float px3 = c.y, py3 = c.z, pz3 = c.w;
        float mn0 = 3.4e38f, mn1 = 3.4e38f, mn2 = 3.4e38f, mn3 = 3.4e38f;

        for (int j = 0; j < M; ++j) {
            float4 cj = col[j];  // LDS broadcast read, conflict-free
            float dx, dy, dz, s;
            dx = px0 - cj.x; dy = py0 - cj.y; dz = pz0 - cj.z;
            s = fmaf(dx, dx, fmaf(dy, dy, dz * dz)); mn0 = fminf(mn0, s);
            dx = px1 - cj.x; dy = py1 - cj.y; dz = pz1 - cj.z;
            s = fmaf(dx, dx, fmaf(dy, dy, dz * dz)); mn1 = fminf(mn1, s);
            dx = px2 - cj.x; dy = py2 - cj.y; dz = pz2 - cj.z;
            s = fmaf(dx, dx, fmaf(dy, dy, dz * dz)); mn2 = fminf(mn2, s);
            dx = px3 - cj.x; dy = py3 - cj.y; dz = pz3 - cj.z;
            s = fmaf(dx, dx, fmaf(dy, dy, dz * dz)); mn3 = fminf(mn3, s);
        }
        // sqrt is monotone: min(sqrt(d2)) == sqrt(min(d2)) -> 4 sqrts, not 120
        lsum += sqrtf(mn0) + sqrtf(mn1) + sqrtf(mn2) + sqrtf(mn3);
    }

    // tail pixels (npix % 4 != 0) — zero iterations for this problem size
    if (tid == 0) {
        for (int p = nquads * 4; p < npix; ++p) {
            float px = adv[3 * p], py = adv[3 * p + 1], pz = adv[3 * p + 2];
            float mn = 3.4e38f;
            for (int j = 0; j < M; ++j) {
                float4 cj = col[j];
                float dx = px - cj.x, dy = py - cj.y, dz = pz - cj.z;
                mn = fminf(mn, fmaf(dx, dx, fmaf(dy, dy, dz * dz)));
            }
            lsum += sqrtf(mn);
        }
    }

    // wave64 reduce, then cross-wave via LDS
    #pragma unroll
    for (int off = 32; off > 0; off >>= 1) lsum += __shfl_down(lsum, off, 64);
    __shared__ float wsum[4];
    int lane = threadIdx.x & 63, wid = threadIdx.x >> 6;
    if (lane == 0) wsum[wid] = lsum;
    __syncthreads();
    if (threadIdx.x == 0)
        partials[blockIdx.x] = wsum[0] + wsum[1] + wsum[2] + wsum[3];
}

__global__ __launch_bounds__(256) void nps_final_kernel(
    const float* __restrict__ partials, int nparts,
    float* __restrict__ out, float invN)
{
    float s = 0.f;
    for (int i = threadIdx.x; i < nparts; i += 256) s += partials[i];
    #pragma unroll
    for (int off = 32; off > 0; off >>= 1) s += __shfl_down(s, off, 64);
    __shared__ float wsum[4];
    int lane = threadIdx.x & 63, wid = threadIdx.x >> 6;
    if (lane == 0) wsum[wid] = s;
    __syncthreads();
    if (threadIdx.x == 0)
        out[0] = (wsum[0] + wsum[1] + wsum[2] + wsum[3]) * invN * COEFF;
}

extern "C" void kernel_launch(void* const* d_in, const int* in_sizes, int n_in,
                              void* d_out, int out_size, void* d_ws, size_t ws_size,
                              hipStream_t stream) {
    const float* adv    = (const float*)d_in[0];
    const float* colors = (const float*)d_in[1];
    float* out = (float*)d_out;

    int npix   = in_sizes[0] / 3;      // 2,097,152
    int M      = in_sizes[1] / 3;      // 30
    int nquads = npix / 4;             // 524,288 (exact)

    int blocks = (nquads + 255) / 256;
    if (blocks > 2048) blocks = 2048;  // 8 blocks/CU -> full occupancy

    float* partials = (float*)d_ws;    // blocks floats; every slot written

    nps_partial_kernel<<<blocks, 256, 0, stream>>>(adv, colors, partials,
                                                   nquads, npix, M);
    nps_final_kernel<<<1, 256, 0, stream>>>(partials, blocks, out,
                                            1.0f / (float)npix);
}